// Round 1
// baseline (383.207 us; speedup 1.0000x reference)
//
#include <hip/hip_runtime.h>
#include <cmath>

#ifndef __has_builtin
#define __has_builtin(x) 0
#endif

#define B_DIM 4096
#define K_DIM 2048
#define N_DIM 2048

#define BM 256
#define BN 128
#define BK 64

typedef __attribute__((ext_vector_type(4))) float f32x4;
typedef __attribute__((ext_vector_type(8))) short bf16x8;
typedef __attribute__((ext_vector_type(8))) unsigned short u16x8;

// ---------- helpers ----------

__device__ __forceinline__ unsigned short f2bf(float f) {
    unsigned int u = __float_as_uint(f);
    u += 0x7fffu + ((u >> 16) & 1u);   // RNE; values here are small exact ints, no NaN
    return (unsigned short)(u >> 16);
}

__device__ __forceinline__ void gl2lds16(const void* g, void* l) {
#if __has_builtin(__builtin_amdgcn_global_load_lds)
    __builtin_amdgcn_global_load_lds((__attribute__((address_space(1))) void*)g,
                                     (__attribute__((address_space(3))) void*)l,
                                     16, 0, 0);
#else
    *(uint4*)l = *(const uint4*)g;
#endif
}

// ---------- prep: fp32 -> bf16 casts ----------

__global__ void cast_x_kernel(const float* __restrict__ X,
                              unsigned short* __restrict__ Xb) {
    size_t i = ((size_t)blockIdx.x * 256 + threadIdx.x) * 8;
    f32x4 a = *(const f32x4*)(X + i);
    f32x4 b = *(const f32x4*)(X + i + 4);
    u16x8 o;
    o[0] = f2bf(a[0]); o[1] = f2bf(a[1]); o[2] = f2bf(a[2]); o[3] = f2bf(a[3]);
    o[4] = f2bf(b[0]); o[5] = f2bf(b[1]); o[6] = f2bf(b[2]); o[7] = f2bf(b[3]);
    *(u16x8*)(Xb + i) = o;
}

__global__ void cast_w_kernel(const float* __restrict__ Wa,
                              const float* __restrict__ Ws,
                              unsigned short* __restrict__ Wab,
                              unsigned short* __restrict__ Wsb) {
    size_t i = ((size_t)blockIdx.x * 256 + threadIdx.x) * 8;
    f32x4 a0 = *(const f32x4*)(Wa + i);
    f32x4 a1 = *(const f32x4*)(Wa + i + 4);
    f32x4 s0 = *(const f32x4*)(Ws + i);
    f32x4 s1 = *(const f32x4*)(Ws + i + 4);
    u16x8 oa, os;
#pragma unroll
    for (int j = 0; j < 4; j++) {
        oa[j]     = f2bf(rintf(a0[j]));  // ste_round fwd = round-half-even
        oa[j + 4] = f2bf(rintf(a1[j]));
        os[j]     = f2bf(rintf(s0[j]));
        os[j + 4] = f2bf(rintf(s1[j]));
    }
    *(u16x8*)(Wab + i) = oa;
    *(u16x8*)(Wsb + i) = os;
}

// ---------- sync primitives (raw, so __syncthreads' vmcnt(0) drain never
// enters the K-loop) ----------

#define VMWAIT_(n) asm volatile("s_waitcnt vmcnt(" #n ")" ::: "memory")
#define VMWAIT(n)  VMWAIT_(n)
#define LGKM0      asm volatile("s_waitcnt lgkmcnt(0)" ::: "memory")
#define FENCE      asm volatile("" ::: "memory")
// empty-asm fences around s_barrier: the barrier intrinsic is not a compiler
// memory fence, so pin LDS reads / DMA issues on their side of it.
#define SBARRIER   do { FENCE; __builtin_amdgcn_s_barrier(); FENCE; } while (0)

// ---------- fused dual-GEMM + DPI neuron update ----------
//
// 256x128 tile, BK=64, 512 threads (8 waves as 4M x 2N), grid 16x16 = 256
// blocks = 1 block/CU.  Double-buffered LDS (2 x 64 KB), staged in HALF-tiles:
//   half h of tile t = { A rows h*128..+128, Wa rows h*64..+64, Ws rows h*64..+64 }
//   = 2048 16B chunks = 4 global_load_lds per thread.
// K-tile is computed in 4 phases, one C-quadrant (mh,nh) x both GEMMs x K=64
// per phase (16 MFMA/wave/phase).  Phase data deps:
//   P0(0,0): A h0 + W h0     P1(0,1): W h1 (A regs reused)
//   P2(1,0): A h1 + W h0     P3(1,1): W h1 (A regs reused)
// Counted vmcnt (T4): stage(t+2,h0) issues at end of P2, stage(t+2,h1) at end
// of P3, so at P0 of tile t exactly 16 loads/thread are outstanding and
// vmcnt(12) retires (t,h0); vmcnt(8) at P1 retires (t,h1).  Never vmcnt(0)
// in the main loop.  Restage safety: P2/P3 put lgkmcnt(0) BEFORE their
// barrier, so every wave's reads of the half about to be overwritten are
// retired chip-wide before any wave issues the DMA.

#define RS 132   // LDS float row stride for epilogue (128 + 4 pad)

#define RD_A(base_, mh_)                                                      \
  _Pragma("unroll") for (int mi = 0; mi < 2; mi++)                            \
  _Pragma("unroll") for (int kk = 0; kk < 2; kk++) {                          \
    const int r_ = (mh_) * 128 + wm * 32 + mi * 16 + frow;                    \
    af[mi][kk] = *(const bf16x8*)((base_) + r_ * 64 + (((kk*4 + kq) ^ swz) * 8)); \
  }

#define RD_B(dst_, base_, nh_)                                                \
  _Pragma("unroll") for (int ni = 0; ni < 2; ni++)                            \
  _Pragma("unroll") for (int kk = 0; kk < 2; kk++) {                          \
    const int r_ = (nh_) * 64 + wn * 32 + ni * 16 + frow;                     \
    dst_[ni][kk] = *(const bf16x8*)((base_) + r_ * 64 + (((kk*4 + kq) ^ swz) * 8)); \
  }

#define MFMAQ(mh_, nh_)                                                       \
  _Pragma("unroll") for (int kk = 0; kk < 2; kk++)                            \
  _Pragma("unroll") for (int mi = 0; mi < 2; mi++)                            \
  _Pragma("unroll") for (int ni = 0; ni < 2; ni++) {                          \
    accA[mh_][nh_][mi][ni] = __builtin_amdgcn_mfma_f32_16x16x32_bf16(         \
        af[mi][kk], ba[ni][kk], accA[mh_][nh_][mi][ni], 0, 0, 0);             \
    accS[mh_][nh_][mi][ni] = __builtin_amdgcn_mfma_f32_16x16x32_bf16(         \
        af[mi][kk], bs[ni][kk], accS[mh_][nh_][mi][ni], 0, 0, 0);             \
  }

// stage one half-tile: LDS dst is linear (wave-uniform base + lane*16); the
// XOR chunk swizzle is applied to the GLOBAL source so ds_read_b128 with
// (jb ^ (row&7)) is bank-conflict-free (proven: 0 conflicts in counters).
#define STAGE_HALF(t2_, h_)                                                   \
{                                                                             \
  unsigned short* bb_ = (unsigned short*)(smem + ((t2_) & 1) * 65536);        \
  const int kst_ = (t2_) * BK;                                                \
  _Pragma("unroll") for (int j = 0; j < 2; j++) {                             \
    const int ca_ = j * 512 + tid;                                            \
    const int rl_ = (h_) * 128 + (ca_ >> 3);                                  \
    const int js_ = (ca_ & 7) ^ (rl_ & 7);                                    \
    gl2lds16(Xb + (size_t)(m0 + rl_) * K_DIM + kst_ + js_ * 8,                \
             bb_ + ((h_) * 1024 + ca_) * 8);                                  \
  }                                                                           \
  {                                                                           \
    const int rl_ = (h_) * 64 + (tid >> 3);                                   \
    const int js_ = (tid & 7) ^ (rl_ & 7);                                    \
    const size_t go_ = (size_t)(n0 + rl_) * K_DIM + kst_ + js_ * 8;           \
    gl2lds16(Wab + go_, bb_ + 16384 + ((h_) * 512 + tid) * 8);                \
    gl2lds16(Wsb + go_, bb_ + 24576 + ((h_) * 512 + tid) * 8);                \
  }                                                                           \
}

#define TILE(t_, VM0, VM1, DOSTG)                                             \
{                                                                             \
  const unsigned short* sAb  = (const unsigned short*)(smem + ((t_) & 1) * 65536); \
  const unsigned short* sWab = sAb + 16384;                                   \
  const unsigned short* sWsb = sAb + 24576;                                   \
  bf16x8 af[2][2], ba[2][2], bs[2][2];                                        \
  /* P0: quadrant (0,0) -- needs (t,h0) landed in every wave */               \
  VMWAIT(VM0); SBARRIER;                                                      \
  RD_A(sAb, 0);                                                               \
  RD_B(ba, sWab, 0); RD_B(bs, sWsb, 0);                                       \
  LGKM0; __builtin_amdgcn_sched_barrier(0);                                   \
  __builtin_amdgcn_s_setprio(1); MFMAQ(0, 0); __builtin_amdgcn_s_setprio(0);  \
  /* P1: quadrant (0,1) -- needs (t,h1); A frags reused from P0 */            \
  VMWAIT(VM1); SBARRIER;                                                      \
  RD_B(ba, sWab, 1); RD_B(bs, sWsb, 1);                                       \
  LGKM0; __builtin_amdgcn_sched_barrier(0);                                   \
  __builtin_amdgcn_s_setprio(1); MFMAQ(0, 1); __builtin_amdgcn_s_setprio(0);  \
  /* P2: quadrant (1,0); after barrier all h0-reads are retired chip-wide */  \
  RD_A(sAb, 1);                                                               \
  RD_B(ba, sWab, 0); RD_B(bs, sWsb, 0);                                       \
  LGKM0; __builtin_amdgcn_sched_barrier(0); SBARRIER;                         \
  __builtin_amdgcn_s_setprio(1); MFMAQ(1, 0); __builtin_amdgcn_s_setprio(0);  \
  if (DOSTG) STAGE_HALF((t_) + 2, 0);                                         \
  /* P3: quadrant (1,1); after barrier all h1-reads are retired chip-wide */  \
  RD_B(ba, sWab, 1); RD_B(bs, sWsb, 1);                                       \
  LGKM0; __builtin_amdgcn_sched_barrier(0); SBARRIER;                         \
  __builtin_amdgcn_s_setprio(1); MFMAQ(1, 1); __builtin_amdgcn_s_setprio(0);  \
  if (DOSTG) STAGE_HALF((t_) + 2, 1);                                         \
}

__global__ __launch_bounds__(512, 2)
void dpi_fused_kernel(const unsigned short* __restrict__ Xb,
                      const unsigned short* __restrict__ Wab,
                      const unsigned short* __restrict__ Wsb,
                      const float* __restrict__ gImem,
                      const float* __restrict__ gIampa,
                      const float* __restrict__ gIshunt,
                      const float* __restrict__ gRefr,
                      const float* __restrict__ pIdc,
                      const float* __restrict__ pIwa,
                      const float* __restrict__ pIws,
                      const float* __restrict__ pAlpha,
                      const float* __restrict__ pBeta,
                      float* __restrict__ out,
                      float i0pow, float kexp, float tau_mem, float inv_tau_syn)
{
    __shared__ __align__(16) unsigned char smem[131072];   // 2 x 64 KB dbuf

    const int tid  = threadIdx.x;
    const int lane = tid & 63;
    const int wave = tid >> 6;        // 0..7
    const int wm   = wave >> 1;       // 0..3 (M within quadrant)
    const int wn   = wave & 1;        // 0..1 (N within quadrant)
    const int frow = lane & 15;
    const int kq   = lane >> 4;       // k sub-chunk 0..3
    const int swz  = frow & 7;

    // bijective XCD swizzle: 256 blocks, each XCD gets an 8x4 tile region
    const int lin = blockIdx.x;       // 0..255
    const int xcd = lin & 7;
    const int loc = lin >> 3;         // 0..31
    const int mb  = (xcd & 1) * 8 + (loc >> 2);   // 0..15
    const int nb  = (xcd >> 1) * 4 + (loc & 3);   // 0..15
    const int m0  = mb * BM;
    const int n0  = nb * BN;

    // acc[mh][nh][mi][ni]: 16 f32x4 per GEMM = 128 VGPR total
    f32x4 accA[2][2][2][2], accS[2][2][2][2];
#pragma unroll
    for (int a = 0; a < 2; a++)
#pragma unroll
    for (int b = 0; b < 2; b++)
#pragma unroll
    for (int c = 0; c < 2; c++)
#pragma unroll
    for (int d = 0; d < 2; d++) { accA[a][b][c][d] = (f32x4)0.0f; accS[a][b][c][d] = (f32x4)0.0f; }

    // prologue: stage tiles 0 and 1 (16 loads/thread, FIFO order h0,h1,h0,h1;
    // fences keep the compiler from interleaving halves, which would break
    // the counted-vmcnt arithmetic)
    STAGE_HALF(0, 0); FENCE;
    STAGE_HALF(0, 1); FENCE;
    STAGE_HALF(1, 0); FENCE;
    STAGE_HALF(1, 1); FENCE;

    // main loop: tiles 0..29 stage tiles 2..31.  Peel 30/31 (no stages; the
    // only vmcnt(0) of the loop is the final tile's P1).
#pragma unroll 2
    for (int t = 0; t < 30; ++t) TILE(t, 12, 8, 1);
    TILE(30, 12, 8, 0);
    TILE(31, 4, 0, 0);

    // ---- epilogue: transpose through LDS, contiguous float4 I/O ----
    // (unchanged math; LDS is free -- all reads retired before the last
    // barrier, no DMA outstanding after vmcnt(0))
    const float idc   = *pIdc;
    const float iwa   = *pIwa;
    const float iws   = *pIws;
    const float alpha = *pAlpha;
    const float beta  = *pBeta;

    const size_t plane = (size_t)B_DIM * N_DIM;
    float* __restrict__ oSpike = out;
    float* __restrict__ oImem  = out + plane;
    float* __restrict__ oIampa = out + 2 * plane;
    float* __restrict__ oIsh   = out + 3 * plane;
    float* __restrict__ oRefr  = out + 4 * plane;

    float* na_buf = (float*)smem;            // 64 x RS
    float* ns_buf = na_buf + 64 * RS;        // 2*64*RS*4 = 67584 B <= 128 KB

    const int quad4 = (lane >> 4) << 2;      // 0,4,8,12
    const int col4  = (tid & 31) * 4;        // float4 column
    const int rbase = (tid >> 5) * 4;        // rows rbase..rbase+3 of the step

#pragma unroll
    for (int k = 0; k < 4; ++k) {            // 4 steps of 64 output rows
        // scatter: step k holds global rows m0 + k*64..+63, contributed by
        // waves with wm in {2*(k&1), 2*(k&1)+1}, quadrant mh = k>>1.
        const int mh_e = k >> 1;
        if ((wm >> 1) == (k & 1)) {
            const int lr0 = (wm & 1) * 32;
#pragma unroll
            for (int nh = 0; nh < 2; nh++)
#pragma unroll
            for (int mi = 0; mi < 2; mi++)
#pragma unroll
            for (int ni = 0; ni < 2; ni++) {
                const int lcol = nh * 64 + wn * 32 + ni * 16 + frow;
#pragma unroll
                for (int r = 0; r < 4; r++) {
                    const int lrow = lr0 + mi * 16 + quad4 + r;
                    na_buf[lrow * RS + lcol] = accA[mh_e][nh][mi][ni][r];
                    ns_buf[lrow * RS + lcol] = accS[mh_e][nh][mi][ni][r];
                }
            }
        }
        __syncthreads();

        // contiguous compute + store: 512 threads cover 64 rows x 128 cols;
        // 32 threads per row -> 512 B runs.
#pragma unroll
        for (int q = 0; q < 4; ++q) {
            const int lr   = rbase + q;
            const int grow = m0 + k * 64 + lr;
            const size_t idx = (size_t)grow * N_DIM + n0 + col4;

            const f32x4 na4 = *(const f32x4*)(na_buf + lr * RS + col4);
            const f32x4 ns4 = *(const f32x4*)(ns_buf + lr * RS + col4);
            const f32x4 im4 = *(const f32x4*)(gImem   + idx);
            const f32x4 ia4 = *(const f32x4*)(gIampa  + idx);
            const f32x4 is4 = *(const f32x4*)(gIshunt + idx);
            const f32x4 rf4 = *(const f32x4*)(gRefr   + idx);

            f32x4 sp_o, im_o, ia_o, is_o, rf_o;
#pragma unroll
            for (int e = 0; e < 4; e++) {
                const float na  = na4[e];
                const float ns  = ns4[e];
                const float im  = im4[e];
                const float ia  = ia4[e];
                const float ish = is4[e];
                const float rf  = rf4[e];

                const float dIampa  = -ia * inv_tau_syn;
                const float ia2     = ia + iwa * na;        // IGAIN_AMPA/ITAU_AMPA = 1
                const float dIshunt = -ish * inv_tau_syn;   // TAU_SHUNT == TAU_AMPA
                const float ish2    = ish + iws * ns;

                float Iin = idc + ia2 + 5e-13f - ish2;      // Inmda = I0
                Iin = (rf <= 0.0f) ? Iin : 0.0f;
                Iin = fmaxf(Iin, 5e-13f);

                // 1+exp(-1e-12*(im-1e-12)): |arg| < 1e-21 -> exp == 1.0f exactly
                // in fp32, denominator == 2.0f. powf via v_log/v_exp.
                const float ifb = i0pow *
                    __builtin_amdgcn_exp2f(kexp * __builtin_amdgcn_logf(im)) * 0.5f;
                const float fimem = ifb * 1e12f * (im + 1e-12f);
                const float dImem = (alpha * ((Iin - 1e-12f) - 5e-13f) - beta * im + fimem)
                                    / (tau_mem * (1.0f + 1e-12f / im));
                float im2 = fmaxf(im + dImem * 0.001f, 5e-13f);

                float ia3 = fmaxf(ia2 + dIampa * 0.001f, 5e-13f);
                ia3       = fmaxf(ia3 + dIshunt * 0.001f, 5e-13f);  // faithful to ref bug

                const float spike = (im2 - 1e-12f > 0.0f) ? 1.0f : 0.0f;
                im2 = (spike > 0.0f) ? 5e-13f : im2;
                float rf2 = fmaxf(rf - 0.001f, 0.0f);
                rf2 = (spike > 0.0f) ? 0.0f : rf2;          // REFP = 0

                sp_o[e] = spike; im_o[e] = im2; ia_o[e] = ia3;
                is_o[e] = ish2;  rf_o[e] = rf2;
            }

            *(f32x4*)(oSpike + idx) = sp_o;
            *(f32x4*)(oImem  + idx) = im_o;
            *(f32x4*)(oIampa + idx) = ia_o;
            *(f32x4*)(oIsh   + idx) = is_o;
            *(f32x4*)(oRefr  + idx) = rf_o;
        }
        __syncthreads();
    }
}

// ---------- launch ----------

extern "C" void kernel_launch(void* const* d_in, const int* in_sizes, int n_in,
                              void* d_out, int out_size, void* d_ws, size_t ws_size,
                              hipStream_t stream) {
    (void)in_sizes; (void)n_in; (void)out_size; (void)ws_size;

    const float* X       = (const float*)d_in[0];
    const float* W_ampa  = (const float*)d_in[1];
    const float* W_shunt = (const float*)d_in[2];
    const float* Imem    = (const float*)d_in[3];
    const float* Iampa   = (const float*)d_in[4];
    const float* Ishunt  = (const float*)d_in[5];
    const float* Refr    = (const float*)d_in[6];
    const float* pIdc    = (const float*)d_in[7];
    const float* pIwa    = (const float*)d_in[8];
    const float* pIws    = (const float*)d_in[9];
    const float* pAlpha  = (const float*)d_in[10];
    const float* pBeta   = (const float*)d_in[11];

    unsigned short* Xb  = (unsigned short*)d_ws;                 // 16 MiB
    unsigned short* Wab = Xb  + (size_t)B_DIM * K_DIM;           // 8 MiB
    unsigned short* Wsb = Wab + (size_t)N_DIM * K_DIM;           // 8 MiB

    const float i0pow       = (float)std::pow(5e-13, 1.0 / 1.705);   // I0^(1/(k+1))
    const float kexp        = (float)(0.705 / 1.705);                // k/(k+1)
    const float tau_mem     = (float)(0.025 / 0.705 * 3.0);
    const float inv_tau_syn = (float)(1.0 / (0.025 / 0.705 * 2.0));

    cast_x_kernel<<<dim3((B_DIM * K_DIM) / (256 * 8)), dim3(256), 0, stream>>>(X, Xb);
    cast_w_kernel<<<dim3((N_DIM * K_DIM) / (256 * 8)), dim3(256), 0, stream>>>(
        W_ampa, W_shunt, Wab, Wsb);

    dpi_fused_kernel<<<dim3(256), dim3(512), 0, stream>>>(
        Xb, Wab, Wsb, Imem, Iampa, Ishunt, Refr,
        pIdc, pIwa, pIws, pAlpha, pBeta,
        (float*)d_out, i0pow, kexp, tau_mem, inv_tau_syn);
}

// Round 2
// 344.993 us; speedup vs baseline: 1.1108x; 1.1108x over previous
//
#include <hip/hip_runtime.h>
#include <cmath>

#ifndef __has_builtin
#define __has_builtin(x) 0
#endif

#define B_DIM 4096
#define K_DIM 2048
#define N_DIM 2048

#define BM 128
#define BN 128
#define BK 128   // i8: 128 elems = 128 B per row = 8 x 16B chunks (same byte geometry as bf16 BK=64)

typedef __attribute__((ext_vector_type(4))) float f32x4;
typedef __attribute__((ext_vector_type(4))) int i32x4;
typedef __attribute__((ext_vector_type(16))) signed char i8x16;

// ---------- helpers ----------

__device__ __forceinline__ signed char f2i8(float f) {
    int t = __float2int_rn(f);               // round-half-even, matches rintf/ste_round
    t = t < -127 ? -127 : (t > 127 ? 127 : t);
    return (signed char)t;
}

__device__ __forceinline__ void gl2lds16(const void* g, void* l) {
#if __has_builtin(__builtin_amdgcn_global_load_lds)
    __builtin_amdgcn_global_load_lds((__attribute__((address_space(1))) void*)g,
                                     (__attribute__((address_space(3))) void*)l,
                                     16, 0, 0);
#else
    *(uint4*)l = *(const uint4*)g;
#endif
}

// ---------- prep: fp32 -> i8 casts ----------
// X entries are exactly 0.0/1.0; ste_round(W) is integral. i8/i32 GEMM is
// exact (numSyn <= 2048*127 << 2^31), bit-identical to the f32 einsum.

__global__ void cast_x_kernel(const float* __restrict__ X,
                              signed char* __restrict__ Xb) {
    size_t i = ((size_t)blockIdx.x * 256 + threadIdx.x) * 16;
    i8x16 o;
#pragma unroll
    for (int j = 0; j < 16; j += 4) {
        f32x4 a = *(const f32x4*)(X + i + j);
        o[j]     = f2i8(a[0]);
        o[j + 1] = f2i8(a[1]);
        o[j + 2] = f2i8(a[2]);
        o[j + 3] = f2i8(a[3]);
    }
    *(i8x16*)(Xb + i) = o;
}

__global__ void cast_w_kernel(const float* __restrict__ Wa,
                              const float* __restrict__ Ws,
                              signed char* __restrict__ Wab,
                              signed char* __restrict__ Wsb) {
    size_t i = ((size_t)blockIdx.x * 256 + threadIdx.x) * 16;
    i8x16 oa, os;
#pragma unroll
    for (int j = 0; j < 16; j += 4) {
        f32x4 a = *(const f32x4*)(Wa + i + j);
        f32x4 s = *(const f32x4*)(Ws + i + j);
        oa[j]     = f2i8(a[0]); oa[j + 1] = f2i8(a[1]);
        oa[j + 2] = f2i8(a[2]); oa[j + 3] = f2i8(a[3]);
        os[j]     = f2i8(s[0]); os[j + 1] = f2i8(s[1]);
        os[j + 2] = f2i8(s[2]); os[j + 3] = f2i8(s[3]);
    }
    *(i8x16*)(Wab + i) = oa;
    *(i8x16*)(Wsb + i) = os;
}

// ---------- fused dual-GEMM + DPI neuron update ----------
// Proven 128x128/4-wave/2x2 structure from the 114 us bf16 kernel, ported to
// i8 with BK=128: LDS byte-address streams are IDENTICAL (rows are 128 B with
// the same XOR chunk swizzle -> measured 0 bank conflicts), but each
// mfma_i32_16x16x64_i8 covers K=64 per 16B fragment (2x the MACs per LDS
// byte of bf16 16x16x32).  ds-read bytes, MFMA instructions, K-loop barriers
// and staged DMA bytes all halve vs the bf16 version; the LDS port (the
// measured bottleneck, ~2.4x oversubscribed vs the matrix pipe) is relieved.

#define RS 132   // LDS float row stride for epilogue (128 + 4 pad)

__global__ __launch_bounds__(256, 2)
void dpi_fused_kernel(const signed char* __restrict__ Xb,
                      const signed char* __restrict__ Wab,
                      const signed char* __restrict__ Wsb,
                      const float* __restrict__ gImem,
                      const float* __restrict__ gIampa,
                      const float* __restrict__ gIshunt,
                      const float* __restrict__ gRefr,
                      const float* __restrict__ pIdc,
                      const float* __restrict__ pIwa,
                      const float* __restrict__ pIws,
                      const float* __restrict__ pAlpha,
                      const float* __restrict__ pBeta,
                      float* __restrict__ out,
                      float i0pow, float kexp, float tau_mem, float inv_tau_syn)
{
    __shared__ __align__(16) unsigned char smem[49152];
    signed char* sA  = (signed char*)smem;             // 16 KB (128 x 128 i8)
    signed char* sWa = (signed char*)(smem + 16384);   // 16 KB
    signed char* sWs = (signed char*)(smem + 32768);   // 16 KB
    float* na_buf = (float*)smem;                      // 32*RS*4 = 16896 B
    float* ns_buf = (float*)(smem + 16896);            // 16896 B

    const int tid  = threadIdx.x;
    const int lane = tid & 63;
    const int wave = tid >> 6;

    // XCD-aware swizzle: 8 XCDs, each gets an 8x8 block region (1024x1024 elems)
    const int lin = blockIdx.x;                 // 0..511
    const int xcd = lin & 7;
    const int loc = lin >> 3;                   // 0..63
    const int mb  = (xcd & 3) * 8 + (loc & 7);  // 0..31
    const int nb  = (xcd >> 2) * 8 + (loc >> 3);// 0..15
    const int m0  = mb * BM;
    const int n0  = nb * BN;

    const int wm = (wave & 1) * 64;
    const int wn = (wave >> 1) * 64;

    i32x4 accA[4][4], accS[4][4];
#pragma unroll
    for (int i = 0; i < 4; i++)
#pragma unroll
        for (int j = 0; j < 4; j++) { accA[i][j] = (i32x4)0; accS[i][j] = (i32x4)0; }

    const int frow = lane & 15;           // m (or n) within a 16-frag
    const int kq   = lane >> 4;           // 0..3 -> k sub-chunk
    const int swzr = frow & 7;            // row part of the XOR swizzle

    for (int k0 = 0; k0 < K_DIM; k0 += BK) {
        // stage 3 tiles of 128x128 i8 (16KB each) = 1024 16B chunks each.
        // LDS dst is forced contiguous (base + lane*16); we XOR-swizzle the
        // GLOBAL source chunk so that row r's chunk j lands at slot j^(r&7).
#pragma unroll
        for (int j = 0; j < 4; j++) {
            int c    = j * 256 + tid;          // LDS chunk 0..1023
            int row  = c >> 3;
            int jsrc = (c & 7) ^ (row & 7);    // source 16B chunk within row
            size_t goffA = (size_t)(m0 + row) * K_DIM + k0 + jsrc * 16;
            size_t goffW = (size_t)(n0 + row) * K_DIM + k0 + jsrc * 16;
            gl2lds16(Xb  + goffA, sA  + c * 16);
            gl2lds16(Wab + goffW, sWa + c * 16);
            gl2lds16(Wsb + goffW, sWs + c * 16);
        }
        __syncthreads();

#pragma unroll
        for (int kk = 0; kk < 2; kk++) {       // two K=64 steps
            const int jb = kk * 4 + kq;        // 16B chunk index of this lane's k
            i32x4 af[4], ba[4], bs[4];
#pragma unroll
            for (int mi = 0; mi < 4; mi++) {
                const int rA = wm + mi * 16 + frow;
                af[mi] = *(const i32x4*)(sA + rA * 128 + ((jb ^ swzr) * 16));
            }
#pragma unroll
            for (int ni = 0; ni < 4; ni++) {
                const int rB = wn + ni * 16 + frow;
                const int o  = rB * 128 + ((jb ^ swzr) * 16);
                ba[ni] = *(const i32x4*)(sWa + o);
                bs[ni] = *(const i32x4*)(sWs + o);
            }
#pragma unroll
            for (int mi = 0; mi < 4; mi++)
#pragma unroll
                for (int ni = 0; ni < 4; ni++) {
                    accA[mi][ni] = __builtin_amdgcn_mfma_i32_16x16x64_i8(af[mi], ba[ni], accA[mi][ni], 0, 0, 0);
                    accS[mi][ni] = __builtin_amdgcn_mfma_i32_16x16x64_i8(af[mi], bs[ni], accS[mi][ni], 0, 0, 0);
                }
        }
        __syncthreads();
    }

    // ---- epilogue: transpose through LDS, then contiguous float4 I/O ----
    const float idc   = *pIdc;
    const float iwa   = *pIwa;
    const float iws   = *pIws;
    const float alpha = *pAlpha;
    const float beta  = *pBeta;

    const size_t plane = (size_t)B_DIM * N_DIM;
    float* __restrict__ oSpike = out;
    float* __restrict__ oImem  = out + plane;
    float* __restrict__ oIampa = out + 2 * plane;
    float* __restrict__ oIsh   = out + 3 * plane;
    float* __restrict__ oRefr  = out + 4 * plane;

    const int rowgroup = wm >> 6;          // 0 or 1
    const int quad4    = (lane >> 4) << 2; // 0,4,8,12
    const int cseg     = (tid & 31) * 4;   // float4 column
    const int rgrp     = tid >> 5;         // 0..7 -> rows rgrp*4..+3

#pragma unroll
    for (int s = 0; s < 4; s++) {          // s == mi: 32 rows of the tile per step
        // scatter fragments into LDS (C/D layout: col=lane&15, row=quad*4+r;
        // dtype-independent, so identical for i8 -> i32 acc)
#pragma unroll
        for (int ni = 0; ni < 4; ni++) {
            const int lcol = wn + ni * 16 + (lane & 15);
#pragma unroll
            for (int r = 0; r < 4; r++) {
                const int lrow = rowgroup * 16 + quad4 + r;
                na_buf[lrow * RS + lcol] = (float)accA[s][ni][r];
                ns_buf[lrow * RS + lcol] = (float)accS[s][ni][r];
            }
        }
        __syncthreads();

        // contiguous compute + store: each thread owns 4 rows x 1 float4
#pragma unroll
        for (int q = 0; q < 4; q++) {
            const int lrow = rgrp * 4 + q;
            const int grow = m0 + (lrow >> 4) * 64 + s * 16 + (lrow & 15);
            const size_t idx = (size_t)grow * N_DIM + n0 + cseg;

            const f32x4 na4 = *(const f32x4*)(na_buf + lrow * RS + cseg);
            const f32x4 ns4 = *(const f32x4*)(ns_buf + lrow * RS + cseg);
            const f32x4 im4 = *(const f32x4*)(gImem   + idx);
            const f32x4 ia4 = *(const f32x4*)(gIampa  + idx);
            const f32x4 is4 = *(const f32x4*)(gIshunt + idx);
            const f32x4 rf4 = *(const f32x4*)(gRefr   + idx);

            f32x4 sp_o, im_o, ia_o, is_o, rf_o;
#pragma unroll
            for (int e = 0; e < 4; e++) {
                const float na  = na4[e];
                const float ns  = ns4[e];
                const float im  = im4[e];
                const float ia  = ia4[e];
                const float ish = is4[e];
                const float rf  = rf4[e];

                const float dIampa  = -ia * inv_tau_syn;
                const float ia2     = ia + iwa * na;        // IGAIN_AMPA/ITAU_AMPA = 1
                const float dIshunt = -ish * inv_tau_syn;   // TAU_SHUNT == TAU_AMPA
                const float ish2    = ish + iws * ns;

                float Iin = idc + ia2 + 5e-13f - ish2;      // Inmda = I0
                Iin = (rf <= 0.0f) ? Iin : 0.0f;
                Iin = fmaxf(Iin, 5e-13f);

                // 1+exp(-1e-12*(im-1e-12)): |arg| < 1e-21 -> exp == 1.0f exactly
                // in fp32, denominator == 2.0f. powf via v_log/v_exp.
                const float ifb = i0pow *
                    __builtin_amdgcn_exp2f(kexp * __builtin_amdgcn_logf(im)) * 0.5f;
                const float fimem = ifb * 1e12f * (im + 1e-12f);
                const float dImem = (alpha * ((Iin - 1e-12f) - 5e-13f) - beta * im + fimem)
                                    / (tau_mem * (1.0f + 1e-12f / im));
                float im2 = fmaxf(im + dImem * 0.001f, 5e-13f);

                float ia3 = fmaxf(ia2 + dIampa * 0.001f, 5e-13f);
                ia3       = fmaxf(ia3 + dIshunt * 0.001f, 5e-13f);  // faithful to ref bug

                const float spike = (im2 - 1e-12f > 0.0f) ? 1.0f : 0.0f;
                im2 = (spike > 0.0f) ? 5e-13f : im2;
                float rf2 = fmaxf(rf - 0.001f, 0.0f);
                rf2 = (spike > 0.0f) ? 0.0f : rf2;          // REFP = 0

                sp_o[e] = spike; im_o[e] = im2; ia_o[e] = ia3;
                is_o[e] = ish2;  rf_o[e] = rf2;
            }

            *(f32x4*)(oSpike + idx) = sp_o;
            *(f32x4*)(oImem  + idx) = im_o;
            *(f32x4*)(oIampa + idx) = ia_o;
            *(f32x4*)(oIsh   + idx) = is_o;
            *(f32x4*)(oRefr  + idx) = rf_o;
        }
        __syncthreads();
    }
}

// ---------- launch ----------

extern "C" void kernel_launch(void* const* d_in, const int* in_sizes, int n_in,
                              void* d_out, int out_size, void* d_ws, size_t ws_size,
                              hipStream_t stream) {
    (void)in_sizes; (void)n_in; (void)out_size; (void)ws_size;

    const float* X       = (const float*)d_in[0];
    const float* W_ampa  = (const float*)d_in[1];
    const float* W_shunt = (const float*)d_in[2];
    const float* Imem    = (const float*)d_in[3];
    const float* Iampa   = (const float*)d_in[4];
    const float* Ishunt  = (const float*)d_in[5];
    const float* Refr    = (const float*)d_in[6];
    const float* pIdc    = (const float*)d_in[7];
    const float* pIwa    = (const float*)d_in[8];
    const float* pIws    = (const float*)d_in[9];
    const float* pAlpha  = (const float*)d_in[10];
    const float* pBeta   = (const float*)d_in[11];

    signed char* Xb  = (signed char*)d_ws;                 // 8 MiB
    signed char* Wab = Xb  + (size_t)B_DIM * K_DIM;        // 4 MiB
    signed char* Wsb = Wab + (size_t)N_DIM * K_DIM;        // 4 MiB

    const float i0pow       = (float)std::pow(5e-13, 1.0 / 1.705);   // I0^(1/(k+1))
    const float kexp        = (float)(0.705 / 1.705);                // k/(k+1)
    const float tau_mem     = (float)(0.025 / 0.705 * 3.0);
    const float inv_tau_syn = (float)(1.0 / (0.025 / 0.705 * 2.0));

    cast_x_kernel<<<dim3((B_DIM * K_DIM) / (256 * 16)), dim3(256), 0, stream>>>(X, Xb);
    cast_w_kernel<<<dim3((N_DIM * K_DIM) / (256 * 16)), dim3(256), 0, stream>>>(
        W_ampa, W_shunt, Wab, Wsb);

    dpi_fused_kernel<<<dim3(512), dim3(256), 0, stream>>>(
        Xb, Wab, Wsb, Imem, Iampa, Ishunt, Refr,
        pIdc, pIwa, pIws, pAlpha, pBeta,
        (float*)d_out, i0pow, kexp, tau_mem, inv_tau_syn);
}